// Round 7
// baseline (602.296 us; speedup 1.0000x reference)
//
#include <hip/hip_runtime.h>
#include <hip/hip_bf16.h>

typedef __attribute__((ext_vector_type(8))) short bf16x8;
typedef __attribute__((ext_vector_type(4))) float f32x4;

#define GLDS(g, l) \
  __builtin_amdgcn_global_load_lds((const __attribute__((address_space(1))) void*)(g), \
                                   (__attribute__((address_space(3))) void*)(l), 16, 0, 0)

#define MFMA_BF16 __builtin_amdgcn_mfma_f32_16x16x32_bf16

// ---------------- Kernel 1: X fp32 -> bf16 (vectorized, grid-stride) ----------------
__global__ __launch_bounds__(256) void k_cvt_bf16(const float* __restrict__ x,
                                                  __hip_bfloat16* __restrict__ y,
                                                  long n8) {
  long stride = (long)gridDim.x * blockDim.x;
  for (long i = (long)blockIdx.x * blockDim.x + threadIdx.x; i < n8; i += stride) {
    const float4* xin = reinterpret_cast<const float4*>(x) + i * 2;
    float4 v0 = xin[0];
    float4 v1 = xin[1];
    union { __hip_bfloat16 h[8]; int4 v; } o;
    o.h[0] = __float2bfloat16(v0.x);
    o.h[1] = __float2bfloat16(v0.y);
    o.h[2] = __float2bfloat16(v0.z);
    o.h[3] = __float2bfloat16(v0.w);
    o.h[4] = __float2bfloat16(v1.x);
    o.h[5] = __float2bfloat16(v1.y);
    o.h[6] = __float2bfloat16(v1.z);
    o.h[7] = __float2bfloat16(v1.w);
    *reinterpret_cast<int4*>(y + i * 8) = o.v;
  }
}

// ---------------- Kernel 2: assemble W bf16 ----------------
__global__ __launch_bounds__(256) void k_make_w(const float* __restrict__ L,
                                                const float* __restrict__ R,
                                                __hip_bfloat16* __restrict__ W) {
  int o = blockIdx.x;
  int b = o & 63;
  __shared__ float Ls[512];
  Ls[threadIdx.x] = L[(size_t)o * 512 + threadIdx.x];
  Ls[threadIdx.x + 256] = L[(size_t)o * 512 + 256 + threadIdx.x];
  __syncthreads();
  for (int idx = threadIdx.x; idx < 4096; idx += 256) {
    int c = idx >> 6;
    int d = idx & 63;
    float s = 0.f;
#pragma unroll
    for (int r = 0; r < 8; ++r) {
      s += Ls[c * 8 + r] * R[(((size_t)(r * 64 + b) * 64 + c) << 6) + d];
    }
    W[(size_t)o * 4096 + idx] = __float2bfloat16(s);
  }
}

// ---------------- Kernel 3: 256x256 bf16 GEMM, 4-phase counted-vmcnt pipeline --------
// Stage tile t+1 during tile t in 4 half-sets matched to per-phase consumption:
//   P1: stage A-even{j0,j2}(t+1), read+MFMA A[m0-3]xB[n0-1]
//   P2: stage B-low (t+1),        read+MFMA A[m0-3]xB[n2-3]... (B23)
//   P3: stage B-high(t+1),        read+MFMA A[m4-7]xB[n2-3]
//   P4: stage A-odd {j1,j3}(t+1), MFMA A[m4-7]xB[n0-1] (regs only)
// Counted vmcnt PRE-BARRIER at P1/P2/P4 (cross-wave certify-then-publish).
__global__ __launch_bounds__(512, 2) void k_gemm_bt(const __hip_bfloat16* __restrict__ A,
                                                    const __hip_bfloat16* __restrict__ B,
                                                    const float* __restrict__ bias,
                                                    float* __restrict__ C) {
  const int K = 4096, N = 4096, NT = 64;
  __shared__ char lds[131072];
  char* const sAc = lds;          // 2 x 32768: A tile [4 groups][64 rows][128B], swizzled
  char* const sBc = lds + 65536;  // 2 x 32768

  const int tid = threadIdx.x;
  const int lane = tid & 63;
  const int wid = tid >> 6;
  const int wr = wid >> 2;    // 0..1 (M half)
  const int wc = wid & 3;     // 0..3 (N quarter)

  // T1: bijective XCD swizzle (nwg = 1024, divisible by 8)
  const int orig = blockIdx.x;
  const int wg = (orig & 7) * 128 + (orig >> 3);
  const int gm0 = (wg >> 4) * 256;
  const int gn0 = (wg & 15) * 256;

  // ---- staging geometry (pre-swizzled global source, linear LDS dest) ----
  const int sc8 = ((lane & 7) << 4) ^ ((lane >> 3) << 4);  // swizzled byte col
  const char* const Ab = (const char*)(A + (size_t)gm0 * K);
  const char* const Bb = (const char*)(B + (size_t)gn0 * K);

  // A half-set: groups j = 2*g + PAR (g=0,1), 2 gload_lds per wave
  auto STAGE_A = [&](int buf, int kt, int par) {
#pragma unroll
    for (int i = 0; i < 2; ++i) {
      const int u = (wid << 1) + i;            // 0..15
      const int j = ((u >> 3) << 1) + par;     // group
      const int rb = u & 7;                    // 8-row block in group
      const int row = (j << 6) + (rb << 3) + (lane >> 3);
      GLDS(Ab + (size_t)row * 8192 + (size_t)kt * 128 + sc8,
           sAc + buf * 32768 + j * 8192 + rb * 1024);
    }
  };
  // B half-set: rows HALF*32..+31 of each group, 2 gload_lds per wave
  auto STAGE_B = [&](int buf, int kt, int half) {
#pragma unroll
    for (int i = 0; i < 2; ++i) {
      const int u = (wid << 1) + i;            // 0..15
      const int j = u >> 2;                    // group 0..3
      const int rb = u & 3;                    // 8-row block in half
      const int row = (j << 6) + (half << 5) + (rb << 3) + (lane >> 3);
      GLDS(Bb + (size_t)row * 8192 + (size_t)kt * 128 + sc8,
           sBc + buf * 32768 + j * 8192 + (half << 12) + (rb << 10));
    }
  };

  // ---- fragment-read geometry (swizzled ds_read) ----
  const int lr = lane & 15;
  const int lk = lane >> 4;
  const int kx0 = (lk << 4) ^ ((lr & 7) << 4);
  const int kx1 = (64 + (lk << 4)) ^ ((lr & 7) << 4);
  const char* const rA0 = sAc + (((wr << 7) + lr) << 7) + kx0;
  const char* const rA1 = sAc + (((wr << 7) + lr) << 7) + kx1;
  const char* const rB0 = sBc + (((wc << 6) + lr) << 7) + kx0;
  const char* const rB1 = sBc + (((wc << 6) + lr) << 7) + kx1;

#define PREFA(DST, BUF, MOFS)                                                \
  _Pragma("unroll")                                                          \
  for (int m = 0; m < 4; ++m) {                                              \
    DST[m][0] = *(const bf16x8*)(rA0 + (BUF) * 32768 + ((MOFS) + m) * 2048); \
    DST[m][1] = *(const bf16x8*)(rA1 + (BUF) * 32768 + ((MOFS) + m) * 2048); \
  }

#define PREFB(DST, BUF, NOFS)                                                \
  _Pragma("unroll")                                                          \
  for (int n = 0; n < 2; ++n) {                                              \
    DST[n][0] = *(const bf16x8*)(rB0 + (BUF) * 32768 + ((NOFS) + n) * 2048); \
    DST[n][1] = *(const bf16x8*)(rB1 + (BUF) * 32768 + ((NOFS) + n) * 2048); \
  }

#define MFMA8X(AF, BF, MB, NB)                                               \
  _Pragma("unroll")                                                          \
  for (int m = 0; m < 4; ++m) {                                              \
    acc[(MB) + m][(NB) + 0] =                                                \
        MFMA_BF16(AF[m][0], BF[0][0], acc[(MB) + m][(NB) + 0], 0, 0, 0);     \
    acc[(MB) + m][(NB) + 0] =                                                \
        MFMA_BF16(AF[m][1], BF[0][1], acc[(MB) + m][(NB) + 0], 0, 0, 0);     \
    acc[(MB) + m][(NB) + 1] =                                                \
        MFMA_BF16(AF[m][0], BF[1][0], acc[(MB) + m][(NB) + 1], 0, 0, 0);     \
    acc[(MB) + m][(NB) + 1] =                                                \
        MFMA_BF16(AF[m][1], BF[1][1], acc[(MB) + m][(NB) + 1], 0, 0, 0);     \
  }

#define LGKM0 asm volatile("s_waitcnt lgkmcnt(0)" ::: "memory")
#define SBAR0 __builtin_amdgcn_sched_barrier(0)
#define VMC4 asm volatile("s_waitcnt vmcnt(4)" ::: "memory")
#define VMC2 asm volatile("s_waitcnt vmcnt(2)" ::: "memory")
#define VMC0 asm volatile("s_waitcnt vmcnt(0)" ::: "memory")

  f32x4 acc[8][4];
#pragma unroll
  for (int m = 0; m < 8; ++m)
#pragma unroll
    for (int n = 0; n < 4; ++n) acc[m][n] = (f32x4){0.f, 0.f, 0.f, 0.f};

  bf16x8 a0[4][2], a1[4][2], bb0[2][2], bb1[2][2];

  // ---- prologue: stage full tile 0 (8 loads), drain once, publish ----
  STAGE_A(0, 0, 0);
  STAGE_B(0, 0, 0);
  STAGE_B(0, 0, 1);
  STAGE_A(0, 0, 1);
  VMC0;
  SBAR0;
  __builtin_amdgcn_s_barrier();

  for (int t = 0; t < NT; ++t) {
    const int buf = t & 1, nb = buf ^ 1;
    const bool more = (t + 1 < NT);

    // ======== P1 ========
    PREFA(a0, buf, 0) PREFB(bb0, buf, 0)
    if (more) { STAGE_A(nb, t + 1, 0); VMC4; } else { VMC2; }
    SBAR0;
    __builtin_amdgcn_s_barrier();
    LGKM0; SBAR0;
    __builtin_amdgcn_s_setprio(1);
    MFMA8X(a0, bb0, 0, 0)
    __builtin_amdgcn_s_setprio(0);
    __builtin_amdgcn_s_barrier();

    // ======== P2 ========
    PREFB(bb1, buf, 2)
    if (more) { STAGE_B(nb, t + 1, 0); VMC4; } else { VMC0; }
    SBAR0;
    __builtin_amdgcn_s_barrier();
    LGKM0; SBAR0;
    __builtin_amdgcn_s_setprio(1);
    MFMA8X(a0, bb1, 0, 2)
    __builtin_amdgcn_s_setprio(0);
    __builtin_amdgcn_s_barrier();

    // ======== P3 ========
    PREFA(a1, buf, 4)
    if (more) STAGE_B(nb, t + 1, 1);
    SBAR0;
    __builtin_amdgcn_s_barrier();
    LGKM0; SBAR0;
    __builtin_amdgcn_s_setprio(1);
    MFMA8X(a1, bb1, 4, 2)
    __builtin_amdgcn_s_setprio(0);
    __builtin_amdgcn_s_barrier();

    // ======== P4 (regs only) ========
    if (more) { STAGE_A(nb, t + 1, 1); VMC4; }
    SBAR0;
    __builtin_amdgcn_s_barrier();
    __builtin_amdgcn_s_setprio(1);
    MFMA8X(a1, bb0, 4, 0)
    __builtin_amdgcn_s_setprio(0);
    __builtin_amdgcn_s_barrier();
  }
  asm volatile("s_waitcnt vmcnt(0) lgkmcnt(0)" ::: "memory");

  // ---- epilogue: C[row][col] = acc + bias[col] ----
  // C/D layout (verified r1-r4): col = lane&15, row = (lane>>4)*4 + j
  const int er = gm0 + (wr << 7) + ((lane >> 4) << 2);
  const int ec = gn0 + (wc << 6) + (lane & 15);
#pragma unroll
  for (int n = 0; n < 4; ++n) {
    const int c = ec + n * 16;
    const float bv = bias[c];
#pragma unroll
    for (int m = 0; m < 8; ++m) {
#pragma unroll
      for (int j = 0; j < 4; ++j) {
        C[(size_t)(er + m * 16 + j) * N + c] = acc[m][n][j] + bv;
      }
    }
  }
}

extern "C" void kernel_launch(void* const* d_in, const int* in_sizes, int n_in,
                              void* d_out, int out_size, void* d_ws, size_t ws_size,
                              hipStream_t stream) {
  const float* x = (const float*)d_in[0];     // [8,2048,4096]
  const float* L = (const float*)d_in[1];     // [64,64,64,8]
  const float* R = (const float*)d_in[2];     // [8,64,64,64]
  const float* bias = (const float*)d_in[3];  // [4096]
  float* out = (float*)d_out;                 // [16384,4096]

  __hip_bfloat16* Wb = (__hip_bfloat16*)d_ws;                                    // 33.5 MB
  __hip_bfloat16* Xb = (__hip_bfloat16*)((char*)d_ws + (size_t)4096 * 4096 * 2); // 134 MB

  const long n8 = (long)16384 * 4096 / 8;
  k_cvt_bf16<<<4096, 256, 0, stream>>>(x, Xb, n8);
  k_make_w<<<4096, 256, 0, stream>>>(L, R, Wb);

  dim3 grid(1024);  // (16384/256) * (4096/256)
  k_gemm_bt<<<grid, 512, 0, stream>>>(Xb, Wb, bias, out);
}

// Round 8
// 569.617 us; speedup vs baseline: 1.0574x; 1.0574x over previous
//
#include <hip/hip_runtime.h>
#include <hip/hip_bf16.h>

typedef __attribute__((ext_vector_type(8))) short bf16x8;
typedef __attribute__((ext_vector_type(4))) float f32x4;

#define GLDS(g, l) \
  __builtin_amdgcn_global_load_lds((const __attribute__((address_space(1))) void*)(g), \
                                   (__attribute__((address_space(3))) void*)(l), 16, 0, 0)

#define MFMA_BF16 __builtin_amdgcn_mfma_f32_16x16x32_bf16

// ---------------- Kernel 1: X fp32 -> bf16 (vectorized, grid-stride) ----------------
__global__ __launch_bounds__(256) void k_cvt_bf16(const float* __restrict__ x,
                                                  __hip_bfloat16* __restrict__ y,
                                                  long n8) {
  long stride = (long)gridDim.x * blockDim.x;
  for (long i = (long)blockIdx.x * blockDim.x + threadIdx.x; i < n8; i += stride) {
    const float4* xin = reinterpret_cast<const float4*>(x) + i * 2;
    float4 v0 = xin[0];
    float4 v1 = xin[1];
    union { __hip_bfloat16 h[8]; int4 v; } o;
    o.h[0] = __float2bfloat16(v0.x);
    o.h[1] = __float2bfloat16(v0.y);
    o.h[2] = __float2bfloat16(v0.z);
    o.h[3] = __float2bfloat16(v0.w);
    o.h[4] = __float2bfloat16(v1.x);
    o.h[5] = __float2bfloat16(v1.y);
    o.h[6] = __float2bfloat16(v1.z);
    o.h[7] = __float2bfloat16(v1.w);
    *reinterpret_cast<int4*>(y + i * 8) = o.v;
  }
}

// ---------------- Kernel 2: assemble W bf16 (low-traffic decomposition) ----------------
// One block per (b,c) pair: W[a*64+b][c*64+d] = sum_r L[((a*64+b)*64+c)*8+r] * R[((r*64+b)*64+c)*64+d]
// Block reads: L 2 KB + R 2 KB (vs 128 KB of R in the old per-row version).
__global__ __launch_bounds__(256) void k_make_w(const float* __restrict__ L,
                                                const float* __restrict__ R,
                                                __hip_bfloat16* __restrict__ W) {
  const int bc = blockIdx.x;       // b*64 + c
  const int b = bc >> 6, c = bc & 63;
  const int d = threadIdx.x & 63;
  const int q = threadIdx.x >> 6;  // a-quarter 0..3
  float Rr[8];
#pragma unroll
  for (int r = 0; r < 8; ++r)
    Rr[r] = R[(((size_t)(r * 64 + b) * 64 + c) << 6) + d];
#pragma unroll 4
  for (int a = q * 16; a < q * 16 + 16; ++a) {
    const float* Lp = L + (((size_t)(a * 64 + b) * 64 + c) << 3);
    float s = 0.f;
#pragma unroll
    for (int r = 0; r < 8; ++r) s = fmaf(Lp[r], Rr[r], s);
    W[((size_t)(a * 64 + b) << 12) + (c << 6) + d] = __float2bfloat16(s);
  }
}

// ---------------- Kernel 3: 256x256 bf16 GEMM, frag-prefetch pipeline (r4, verified) ---
// 4 phases per K-tile, ds_reads issued one phase ahead (drain under MFMA),
// ONE barrier per K-tile, vmcnt(0)+lgkm(0) pre-barrier (fully latency-covered:
// waits on staging issued 1.5 tiles earlier). T1+T2+T5. Bias seeded into acc.
__global__ __launch_bounds__(512, 2) void k_gemm_bt(const __hip_bfloat16* __restrict__ A,
                                                    const __hip_bfloat16* __restrict__ B,
                                                    const float* __restrict__ bias,
                                                    float* __restrict__ C) {
  const int K = 4096, N = 4096, NT = 64;
  __shared__ char lds[131072];
  char* const sAc = lds;          // 2 x 32768: A tile [256][64] bf16, swizzled
  char* const sBc = lds + 65536;  // 2 x 32768

  const int tid = threadIdx.x;
  const int lane = tid & 63;
  const int wid = tid >> 6;
  const int wr = wid >> 2;    // 0..1 (M half)
  const int wc = wid & 3;     // 0..3 (N quarter)

  // T1: bijective XCD swizzle (nwg = 1024, divisible by 8)
  const int orig = blockIdx.x;
  const int wg = (orig & 7) * 128 + (orig >> 3);
  const int gm0 = (wg >> 4) * 256;
  const int gn0 = (wg & 15) * 256;

  // ---- staging geometry (pre-swizzled global source, linear LDS dest) ----
  const int crow = tid >> 3;                              // row within 64-row group
  const int scol = ((tid & 7) << 4) ^ ((crow & 7) << 4);  // swizzled byte col
  const int voff = crow * 8192 + scol;                    // per-lane global byte offset
  const int wbase = (tid >> 6) << 10;                     // wave-uniform LDS chunk base
  const char* const Ab = (const char*)(A + (size_t)gm0 * K);
  const char* const Bb = (const char*)(B + (size_t)gn0 * K);

#define STAGEA(BUF, TS)                                                      \
  _Pragma("unroll")                                                          \
  for (int j = 0; j < 4; ++j)                                                \
    GLDS(Ab + (size_t)((TS) * 128 + j * 524288) + voff,                      \
         sAc + (BUF) * 32768 + j * 8192 + wbase);

#define STAGEB(BUF, TS)                                                      \
  _Pragma("unroll")                                                          \
  for (int j = 0; j < 4; ++j)                                                \
    GLDS(Bb + (size_t)((TS) * 128 + j * 524288) + voff,                      \
         sBc + (BUF) * 32768 + j * 8192 + wbase);

  // ---- fragment-read geometry (swizzled ds_read) ----
  const int lr = lane & 15;
  const int lk = lane >> 4;
  const int kx0 = (lk << 4) ^ ((lr & 7) << 4);
  const int kx1 = (64 + (lk << 4)) ^ ((lr & 7) << 4);
  const char* const rA0 = sAc + (((wr << 7) + lr) << 7) + kx0;
  const char* const rA1 = sAc + (((wr << 7) + lr) << 7) + kx1;
  const char* const rB0 = sBc + (((wc << 6) + lr) << 7) + kx0;
  const char* const rB1 = sBc + (((wc << 6) + lr) << 7) + kx1;

#define PREFA(DST, BUF, MOFS)                                                \
  _Pragma("unroll")                                                          \
  for (int m = 0; m < 4; ++m) {                                              \
    DST[m][0] = *(const bf16x8*)(rA0 + (BUF) * 32768 + ((MOFS) + m) * 2048); \
    DST[m][1] = *(const bf16x8*)(rA1 + (BUF) * 32768 + ((MOFS) + m) * 2048); \
  }

#define PREFB(DST, BUF, NOFS)                                                \
  _Pragma("unroll")                                                          \
  for (int n = 0; n < 2; ++n) {                                              \
    DST[n][0] = *(const bf16x8*)(rB0 + (BUF) * 32768 + ((NOFS) + n) * 2048); \
    DST[n][1] = *(const bf16x8*)(rB1 + (BUF) * 32768 + ((NOFS) + n) * 2048); \
  }

#define MFMA8X(AF, BF, MB, NB)                                               \
  _Pragma("unroll")                                                          \
  for (int m = 0; m < 4; ++m) {                                              \
    acc[(MB) + m][(NB) + 0] =                                                \
        MFMA_BF16(AF[m][0], BF[0][0], acc[(MB) + m][(NB) + 0], 0, 0, 0);     \
    acc[(MB) + m][(NB) + 0] =                                                \
        MFMA_BF16(AF[m][1], BF[0][1], acc[(MB) + m][(NB) + 0], 0, 0, 0);     \
    acc[(MB) + m][(NB) + 1] =                                                \
        MFMA_BF16(AF[m][0], BF[1][0], acc[(MB) + m][(NB) + 1], 0, 0, 0);     \
    acc[(MB) + m][(NB) + 1] =                                                \
        MFMA_BF16(AF[m][1], BF[1][1], acc[(MB) + m][(NB) + 1], 0, 0, 0);     \
  }

#define LGKM0 asm volatile("s_waitcnt lgkmcnt(0)" ::: "memory")
#define SBAR0 __builtin_amdgcn_sched_barrier(0)

  // epilogue coordinates (hoisted: needed for bias-seeded acc init)
  const int er = gm0 + (wr << 7) + ((lane >> 4) << 2);
  const int ec = gn0 + (wc << 6) + (lane & 15);

  f32x4 acc[8][4];
#pragma unroll
  for (int n = 0; n < 4; ++n) {
    const float bv = bias[ec + n * 16];
#pragma unroll
    for (int m = 0; m < 8; ++m) acc[m][n] = (f32x4){bv, bv, bv, bv};
  }

  bf16x8 aX[4][2], aY[4][2], b0[2][2], b2[2][2];

  // ---- prologue: stage tiles 0,1; wait tile 0 (A1,B1 = 8 loads stay in flight) ----
  STAGEA(0, 0) STAGEB(0, 0) STAGEA(1, 1) STAGEB(1, 1)
  asm volatile("s_waitcnt vmcnt(8)" ::: "memory");
  SBAR0;
  __builtin_amdgcn_s_barrier();
  PREFA(aX, 0, 0) PREFB(b0, 0, 0)

  // Phase order per tile: P1(m03,n01,aX) P2(m47,n01,aY) P3(m03,n23,aX) P4(m47,n23,aY)
  // Prefetch: P1->aY=A47(t)  P2->b2=B23(t)  P3->b0=B01(t+1)  P4->aX=A03(t+1)
  // Staging:  P3: A(t+2)->BUF post-barrier;  P4: B(t+2)->BUF
#define TILE(BUF, T)                                                         \
  {                                                                          \
    const int tS = ((T) + 2 < NT) ? (T) + 2 : NT - 1;                        \
    /* P1 */                                                                 \
    LGKM0; SBAR0;                                                            \
    PREFA(aY, BUF, 4)                                                        \
    SBAR0;                                                                   \
    __builtin_amdgcn_s_setprio(1);                                           \
    MFMA8X(aX, b0, 0, 0)                                                     \
    __builtin_amdgcn_s_setprio(0);                                           \
    /* P2 */                                                                 \
    LGKM0; SBAR0;                                                            \
    PREFB(b2, BUF, 2)                                                        \
    SBAR0;                                                                   \
    __builtin_amdgcn_s_setprio(1);                                           \
    MFMA8X(aY, b0, 4, 0)                                                     \
    __builtin_amdgcn_s_setprio(0);                                           \
    /* P3: the one barrier per tile (drain fully covered: staging is 1.5 tiles old) */ \
    asm volatile("s_waitcnt lgkmcnt(0) vmcnt(0)" ::: "memory");              \
    SBAR0;                                                                   \
    __builtin_amdgcn_s_barrier();                                            \
    STAGEA(BUF, tS)                                                          \
    PREFB(b0, (BUF) ^ 1, 0)                                                  \
    SBAR0;                                                                   \
    __builtin_amdgcn_s_setprio(1);                                           \
    MFMA8X(aX, b2, 0, 2)                                                     \
    __builtin_amdgcn_s_setprio(0);                                           \
    /* P4 (no wait needed at entry) */                                       \
    SBAR0;                                                                   \
    STAGEB(BUF, tS)                                                          \
    PREFA(aX, (BUF) ^ 1, 0)                                                  \
    SBAR0;                                                                   \
    __builtin_amdgcn_s_setprio(1);                                           \
    MFMA8X(aY, b2, 4, 2)                                                     \
    __builtin_amdgcn_s_setprio(0);                                           \
  }

  for (int t = 0; t < NT; t += 2) {
    TILE(0, t)
    TILE(1, t + 1)
  }
  asm volatile("s_waitcnt vmcnt(0) lgkmcnt(0)" ::: "memory");

  // ---- epilogue: C[row][col] = acc (bias already seeded) ----
#pragma unroll
  for (int n = 0; n < 4; ++n) {
    const int c = ec + n * 16;
#pragma unroll
    for (int m = 0; m < 8; ++m) {
#pragma unroll
      for (int j = 0; j < 4; ++j) {
        C[(size_t)(er + m * 16 + j) * N + c] = acc[m][n][j];
      }
    }
  }
}

extern "C" void kernel_launch(void* const* d_in, const int* in_sizes, int n_in,
                              void* d_out, int out_size, void* d_ws, size_t ws_size,
                              hipStream_t stream) {
  const float* x = (const float*)d_in[0];     // [8,2048,4096]
  const float* L = (const float*)d_in[1];     // [64,64,64,8]
  const float* R = (const float*)d_in[2];     // [8,64,64,64]
  const float* bias = (const float*)d_in[3];  // [4096]
  float* out = (float*)d_out;                 // [16384,4096]

  __hip_bfloat16* Wb = (__hip_bfloat16*)d_ws;                                    // 33.5 MB
  __hip_bfloat16* Xb = (__hip_bfloat16*)((char*)d_ws + (size_t)4096 * 4096 * 2); // 134 MB

  const long n8 = (long)16384 * 4096 / 8;
  k_cvt_bf16<<<4096, 256, 0, stream>>>(x, Xb, n8);
  k_make_w<<<4096, 256, 0, stream>>>(L, R, Wb);  // one block per (b,c)

  dim3 grid(1024);  // (16384/256) * (4096/256)
  k_gemm_bt<<<grid, 512, 0, stream>>>(Xb, Wb, bias, out);
}